// Round 12
// baseline (528.706 us; speedup 1.0000x reference)
//
#include <hip/hip_runtime.h>

typedef float f32x2 __attribute__((ext_vector_type(2)));
typedef float f32x4 __attribute__((ext_vector_type(4)));

#define NN 16384
#define NCB 8
#define DIM 32
#define CB 1024
#define RPB 512

// packed 2xFP32 FMA; each half bit-identical to scalar fmaf (frozen chain).
__device__ __forceinline__ f32x2 pkfma(f32x2 a, f32x2 b, f32x2 c) {
    f32x2 d = c;
    asm("v_pk_fma_f32 %0, %1, %2, %0" : "+v"(d) : "v"(a), "v"(b));
    return d;
}

// one DPP min step; inactive/OOB lanes keep their own value (old = v).
#define DPPMIN_F(v, ctrl)                                                     \
    v = fminf(v, __int_as_float(__builtin_amdgcn_update_dpp(                  \
               __float_as_int(v), __float_as_int(v), (ctrl), 0xf, 0xf,        \
               false)))
#define DPPMIN_U(v, ctrl)                                                     \
    {                                                                         \
        unsigned s_ = (unsigned)__builtin_amdgcn_update_dpp(                  \
            (int)(v), (int)(v), (ctrl), 0xf, 0xf, false);                     \
        v = (v < s_) ? v : s_;                                                \
    }

// Precompute: csqb[k*CB+c] = ||c||^2 + bias (frozen chain);
//             xsqb[p] = ||x_p||^2 (frozen chain), p = n*NCB+k.
__global__ __launch_bounds__(256) void vq_pre(const float* __restrict__ cb,
                                              const float* __restrict__ rb,
                                              const float* __restrict__ x,
                                              float* __restrict__ csqb,
                                              float* __restrict__ xsqb) {
    const int gid = blockIdx.x * 256 + threadIdx.x;
    if (gid < NCB * CB) {
        const f32x4* c4 = (const f32x4*)(cb + (size_t)gid * DIM);
        float s0 = 0.f, s1 = 0.f, s2 = 0.f, s3 = 0.f;
#pragma unroll
        for (int j = 0; j < 8; ++j) {
            f32x4 v = c4[j];
            s0 = fmaf(v.x, v.x, s0);
            s1 = fmaf(v.y, v.y, s1);
            s2 = fmaf(v.z, v.z, s2);
            s3 = fmaf(v.w, v.w, s3);
        }
        csqb[gid] = ((s0 + s1) + (s2 + s3)) + rb[gid];
    }
    const int p = gid - NCB * CB;
    if (p >= 0 && p < NN * NCB) {
        const f32x4* x4 = (const f32x4*)(x + (size_t)p * DIM);
        float q0 = 0.f, q1 = 0.f, q2 = 0.f, q3 = 0.f;
#pragma unroll
        for (int j = 0; j < 8; ++j) {
            f32x4 v = x4[j];
            q0 = fmaf(v.x, v.x, q0);
            q1 = fmaf(v.y, v.y, q1);
            q2 = fmaf(v.z, v.z, q2);
            q3 = fmaf(v.w, v.w, q3);
        }
        xsqb[p] = (q0 + q1) + (q2 + q3);
    }
}

// Fused kernel: 256 blocks (1/CU) x 768 threads (12 waves, 3/SIMD).
//   waves 0-7 (compute): lane-resident entries. Lane l of wave w holds
//     entries c0=w*128+l, c1=c0+64 in 64 VGPRs (loaded once from the
//     LDS-transposed pair layout cbP[16][1024]). Rows stream: per row one
//     uniform x load + 32 pkfma (bit-frozen chain) + zero-LDS DPP reduce:
//     6-step min(dist) -> readlane63; then u32-min over indices whose dist
//     equals the min (= np argmin first-occurrence, tie-exact).
//   waves 8-11 (storers): stream the block's 2 MB one_hot zero-fill from
//     t=0; never drained until the final barrier (mid barrier is raw
//     s_barrier + lgkmcnt only).
// Per-wave (dist,idx) published to LDS; final barrier (drains zeros) then
// combine 8 partials + scatter idx / x_hat / 1.0.
__global__ __launch_bounds__(768, 1) void vq_fused(
    const float* __restrict__ x, const float* __restrict__ cb,
    const float* __restrict__ csqb, const float* __restrict__ xsqb,
    float* __restrict__ xhat, float* __restrict__ onehot,
    float* __restrict__ idxf) {
    __shared__ f32x2 cbP[16][CB];           // 128 KB transposed pair layout
    __shared__ float pd[8][RPB];            // 16 KB
    __shared__ unsigned short pi[8][RPB];   // 8 KB  -> 152 KB total

    const int tid = threadIdx.x;
    const int w = tid >> 6;
    const int lane = tid & 63;
    const int k = blockIdx.x & (NCB - 1);
    const int n0 = (blockIdx.x >> 3) * RPB;

    const f32x4* cbk4 = (const f32x4*)(cb + (size_t)k * CB * DIM);

    if (w >= 8) {
        // ---- storer wave: zero 128 one_hot rows, coalesced 1KB stores ----
        const int s = w - 8;
        f32x4* oh4 = (f32x4*)onehot;
        const f32x4 z4 = {0.f, 0.f, 0.f, 0.f};
#pragma unroll 4
        for (int rr = 0; rr < 128; ++rr) {
            const size_t rowb =
                ((size_t)(n0 + s * 128 + rr) * NCB + k) * 256;
#pragma unroll
            for (int j = 0; j < 4; ++j) oh4[rowb + j * 64 + lane] = z4;
        }
        // mid barrier: NO vmcnt wait -> zeros stay in flight
        asm volatile("s_waitcnt lgkmcnt(0)\n\ts_barrier" ::: "memory");
        __syncthreads();  // final: drains this wave's zeros (vmcnt 0)
        return;
    }

    // ---- compute wave: stage transposed codebook (entries tid, tid+512) ----
#pragma unroll
    for (int e2 = 0; e2 < 2; ++e2) {
        const int e = tid + e2 * 512;
        const f32x4* src = cbk4 + (size_t)e * 8;
#pragma unroll
        for (int j = 0; j < 8; ++j) {
            f32x4 v = src[j];
            cbP[2 * j][e] = (f32x2){v.x, v.y};
            cbP[2 * j + 1][e] = (f32x2){v.z, v.w};
        }
    }
    asm volatile("s_waitcnt lgkmcnt(0)\n\ts_barrier" ::: "memory");

    // ---- lane-resident entries (loaded once; conflict-free 2-way reads) ----
    const int c0 = w * 128 + lane;
    const int c1 = c0 + 64;
    f32x2 ce0[16], ce1[16];
#pragma unroll
    for (int p = 0; p < 16; ++p) {
        ce0[p] = cbP[p][c0];
        ce1[p] = cbP[p][c1];
    }
    const float cq0 = csqb[(size_t)k * CB + c0];
    const float cq1 = csqb[(size_t)k * CB + c1];

    // ---- row stream ----
#pragma unroll 2
    for (int r = 0; r < RPB; ++r) {
        const size_t pidx = (size_t)(n0 + r) * NCB + k;
        const f32x4* xp4 = (const f32x4*)(x + pidx * DIM);
        f32x4 xq[8];
#pragma unroll
        for (int j = 0; j < 8; ++j) xq[j] = xp4[j];
        const float xs = xsqb[pidx];

        f32x2 a01 = {0.f, 0.f}, a23 = {0.f, 0.f};
        f32x2 b01 = {0.f, 0.f}, b23 = {0.f, 0.f};
#pragma unroll
        for (int j = 0; j < 8; ++j) {  // frozen chain: j ascending, 4 accs
            const f32x2 lo = {xq[j].x, xq[j].y};
            const f32x2 hi = {xq[j].z, xq[j].w};
            a01 = pkfma(lo, ce0[2 * j], a01);
            a23 = pkfma(hi, ce0[2 * j + 1], a23);
            b01 = pkfma(lo, ce1[2 * j], b01);
            b23 = pkfma(hi, ce1[2 * j + 1], b23);
        }
        const float dot0 = (a01.x + a01.y) + (a23.x + a23.y);
        const float d0 = fmaf(-2.f, dot0, xs + cq0);
        const float dot1 = (b01.x + b01.y) + (b23.x + b23.y);
        const float d1 = fmaf(-2.f, dot1, xs + cq1);

        // wave-min of dist (exact fp32 min, order-independent)
        float mv = fminf(d0, d1);
        DPPMIN_F(mv, 0x111);  // row_shr:1
        DPPMIN_F(mv, 0x112);  // row_shr:2
        DPPMIN_F(mv, 0x114);  // row_shr:4
        DPPMIN_F(mv, 0x118);  // row_shr:8
        DPPMIN_F(mv, 0x142);  // row_bcast15
        DPPMIN_F(mv, 0x143);  // row_bcast31
        const float m = __int_as_float(
            __builtin_amdgcn_readlane(__float_as_int(mv), 63));

        // min index among dist==m  (= np argmin first occurrence, tie-exact)
        unsigned cand = 0xFFFFFFFFu;
        cand = (d1 == m) ? (unsigned)c1 : cand;
        cand = (d0 == m) ? (unsigned)c0 : cand;  // c0 < c1 priority
        DPPMIN_U(cand, 0x111);
        DPPMIN_U(cand, 0x112);
        DPPMIN_U(cand, 0x114);
        DPPMIN_U(cand, 0x118);
        DPPMIN_U(cand, 0x142);
        DPPMIN_U(cand, 0x143);
        const unsigned mi =
            (unsigned)__builtin_amdgcn_readlane((int)cand, 63);

        if (lane == 0) {
            pd[w][r] = m;
            pi[w][r] = (unsigned short)mi;
        }
    }

    __syncthreads();  // partials visible + ALL zero-stores drained

    // ---- combine 8 wave-partials + scatter; thread tid owns row tid ----
    {
        const int r = tid;
        float bd = pd[0][r];
        unsigned bx = pi[0][r];
#pragma unroll
        for (int qq = 1; qq < 8; ++qq) {
            const float dq = pd[qq][r];
            const unsigned iq = pi[qq][r];
            if (dq < bd || (dq == bd && iq < bx)) {  // tie -> lower index
                bd = dq;
                bx = iq;
            }
        }
        const int n = n0 + r;
        idxf[(size_t)n * NCB + k] = (float)bx;
        const f32x4* src = cbk4 + (size_t)bx * 8;
        f32x4* dst = (f32x4*)(xhat + ((size_t)n * NCB + k) * DIM);
#pragma unroll
        for (int j = 0; j < 8; ++j) dst[j] = src[j];
        onehot[((size_t)n * NCB + k) * CB + bx] = 1.0f;
    }
}

extern "C" void kernel_launch(void* const* d_in, const int* in_sizes, int n_in,
                              void* d_out, int out_size, void* d_ws,
                              size_t ws_size, hipStream_t stream) {
    const float* x = (const float*)d_in[0];
    const float* cb = (const float*)d_in[1];
    const float* rb = (const float*)d_in[2];

    float* out = (float*)d_out;
    float* xhat = out;                             // N*NCB*DIM
    float* onehot = out + (size_t)NN * NCB * DIM;  // N*NCB*CB
    float* idxf = onehot + (size_t)NN * NCB * CB;  // N*NCB

    float* csqb = (float*)d_ws;            // 32 KB
    float* xsqb = csqb + NCB * CB;         // 512 KB

    const int pre_total = NCB * CB + NN * NCB;
    vq_pre<<<(pre_total + 255) / 256, 256, 0, stream>>>(cb, rb, x, csqb, xsqb);
    vq_fused<<<(NN / RPB) * NCB, 768, 0, stream>>>(x, cb, csqb, xsqb, xhat,
                                                   onehot, idxf);
}